// Round 5
// baseline (666.947 us; speedup 1.0000x reference)
//
#include <hip/hip_runtime.h>
#include <hip/hip_bf16.h>

#define NN    100000
#define NE    1600000
#define INCH  512
#define HIDCH 256
#define OUTCH 32
#define KHOPS 10

typedef __attribute__((ext_vector_type(8))) short short8;
typedef __attribute__((ext_vector_type(4))) float f32x4;

#define GLOAD_LDS16(gsrc, ldst) \
  __builtin_amdgcn_global_load_lds((const __attribute__((address_space(1))) void*)(gsrc), \
                                   (__attribute__((address_space(3))) void*)(ldst), 16, 0, 0)

#define WAIT_VM(N) asm volatile("s_waitcnt vmcnt(" #N ")" ::: "memory")
#define WAIT_LGKM0() asm volatile("s_waitcnt lgkmcnt(0)" ::: "memory")
#define PIN() __builtin_amdgcn_sched_barrier(0)

// ---------------- workspace layout ----------------
constexpr size_t ws_align(size_t x) { return (x + 255) & ~(size_t)255; }
constexpr size_t OFF_H1   = 0;                                           // [NN][256] bf16
constexpr size_t OFF_HA   = OFF_H1   + ws_align((size_t)NN*HIDCH*2);     // [NN][32] f32
constexpr size_t OFF_HB   = OFF_HA   + ws_align((size_t)NN*OUTCH*4);     // [NN][32] f32
constexpr size_t OFF_W1TH = OFF_HB   + ws_align((size_t)NN*OUTCH*4);     // [256][512] bf16
constexpr size_t OFF_W1TL = OFF_W1TH + ws_align((size_t)HIDCH*INCH*2);
constexpr size_t OFF_W2TH = OFF_W1TL + ws_align((size_t)HIDCH*INCH*2);   // [32][256] bf16
constexpr size_t OFF_W2TL = OFF_W2TH + ws_align((size_t)OUTCH*HIDCH*2);
constexpr size_t OFF_DEG  = OFF_W2TL + ws_align((size_t)OUTCH*HIDCH*2);  // [NN] int
constexpr size_t OFF_DIS  = OFF_DEG  + ws_align((size_t)NN*4);           // [NN] f32
constexpr size_t OFF_RP   = OFF_DIS  + ws_align((size_t)NN*4);           // [NN+1] int
constexpr size_t OFF_CUR  = OFF_RP   + ws_align((size_t)(NN+1)*4);       // [NN] int
constexpr size_t OFF_EPK  = OFF_CUR  + ws_align((size_t)NN*4);           // [NE] int2 (src, norm)
constexpr size_t OFF_PART = OFF_EPK  + ws_align((size_t)NE*8);           // [128] int
constexpr size_t OFF_OFFS = OFF_PART + ws_align(512);                    // [128] int

// ---------------- bf16 helpers ----------------
__device__ __forceinline__ unsigned short bf16_rne(float f) {
  unsigned int u = __float_as_uint(f);
  u += 0x7fffu + ((u >> 16) & 1u);
  return (unsigned short)(u >> 16);
}
__device__ __forceinline__ float bf16_to_f32(unsigned short h) {
  return __uint_as_float(((unsigned int)h) << 16);
}

// ---------------- degree / norm ----------------
__global__ __launch_bounds__(256) void k_count_deg(const int* __restrict__ col,
                                                   int* __restrict__ deg) {
  int e = blockIdx.x * 256 + threadIdx.x;
  if (e < NE) atomicAdd(&deg[col[e]], 1);
}

__global__ __launch_bounds__(256) void k_dis(const int* __restrict__ deg,
                                             float* __restrict__ dis) {
  int v = blockIdx.x * 256 + threadIdx.x;
  if (v < NN) {
    int d = deg[v];
    dis[v] = d > 0 ? rsqrtf((float)d) : 0.0f;
  }
}

// ---------------- exclusive scan over deg (3 kernels) ----------------
__global__ __launch_bounds__(256) void k_scan1(const int* __restrict__ deg,
                                               int* __restrict__ rp,
                                               int* __restrict__ part) {
  __shared__ int s[256];
  int b = blockIdx.x, t = threadIdx.x;
  int base = b * 1024 + t * 4;
  int v0 = (base + 0 < NN) ? deg[base + 0] : 0;
  int v1 = (base + 1 < NN) ? deg[base + 1] : 0;
  int v2 = (base + 2 < NN) ? deg[base + 2] : 0;
  int v3 = (base + 3 < NN) ? deg[base + 3] : 0;
  int tot = v0 + v1 + v2 + v3;
  s[t] = tot;
  __syncthreads();
  for (int d = 1; d < 256; d <<= 1) {
    int x = (t >= d) ? s[t - d] : 0;
    __syncthreads();
    s[t] += x;
    __syncthreads();
  }
  int excl = s[t] - tot;
  if (t == 255) part[b] = s[255];
  if (base + 0 < NN) rp[base + 0] = excl;
  if (base + 1 < NN) rp[base + 1] = excl + v0;
  if (base + 2 < NN) rp[base + 2] = excl + v0 + v1;
  if (base + 3 < NN) rp[base + 3] = excl + v0 + v1 + v2;
}

__global__ __launch_bounds__(128) void k_scan2(const int* __restrict__ part,
                                               int* __restrict__ offs) {
  __shared__ int s[128];
  int t = threadIdx.x;
  int v = (t < 98) ? part[t] : 0;
  s[t] = v;
  __syncthreads();
  for (int d = 1; d < 128; d <<= 1) {
    int x = (t >= d) ? s[t - d] : 0;
    __syncthreads();
    s[t] += x;
    __syncthreads();
  }
  if (t < 98) offs[t] = s[t] - v;
}

__global__ __launch_bounds__(256) void k_scan3(int* __restrict__ rp,
                                               const int* __restrict__ offs,
                                               int* __restrict__ cur) {
  int b = blockIdx.x, t = threadIdx.x;
  int o = offs[b];
  int base = b * 1024 + t * 4;
#pragma unroll
  for (int j = 0; j < 4; ++j) {
    int i = base + j;
    if (i < NN) {
      int r = rp[i] + o;
      rp[i] = r;
      cur[i] = r;
    }
  }
  if (b == 0 && t == 0) rp[NN] = NE;
}

// fill CSR: epk = (src node, bits(dis[row]*dis[col]))
__global__ __launch_bounds__(256) void k_fill(const int* __restrict__ ei,
                                              const float* __restrict__ dis,
                                              int* __restrict__ cur,
                                              int2* __restrict__ epk) {
  int e = blockIdx.x * 256 + threadIdx.x;
  if (e < NE) {
    int r = ei[e], c = ei[NE + e];
    int p = atomicAdd(&cur[c], 1);
    epk[p] = make_int2(r, __float_as_int(dis[r] * dis[c]));
  }
}

// ---------------- split-transpose: dst[n][k] = split(src[k][n]) ----------------
__global__ __launch_bounds__(256) void k_splitT(const float* __restrict__ src,
                                                unsigned short* __restrict__ dh,
                                                unsigned short* __restrict__ dl,
                                                int K, int N) {
  int idx = blockIdx.x * 256 + threadIdx.x;
  if (idx >= K * N) return;
  int n = idx / K, k = idx - n * K;
  float v = src[(size_t)k * N + n];
  unsigned short h = bf16_rne(v);
  dh[idx] = h;
  dl[idx] = bf16_rne(v - bf16_to_f32(h));
}

// ---------------- GEMM1: H1bf = bf16(relu(X @ W1 + b1)), 2-product bf16 MFMA ------
// tile 128(M) x 256(N) x 32(K); 8 waves, wave tile 64x64.
// Counted-vmcnt pipeline: B 1-tile ahead via global_load_lds (never drained to 0
// in steady state), A regs 2 tiles ahead, raw s_barrier x2 per iter.
__global__ __launch_bounds__(512, 2) void k_gemm1(const float* __restrict__ X,
                                                  const unsigned short* __restrict__ W1Th,
                                                  const unsigned short* __restrict__ W1Tl,
                                                  const float* __restrict__ bias1,
                                                  unsigned short* __restrict__ H1bf) {
  __shared__ __align__(16) unsigned short Ah[2][4096];
  __shared__ __align__(16) unsigned short Bh[2][8192], Bl[2][8192];
  const int t = threadIdx.x;
  const int m0 = blockIdx.x * 128;
  const int w = t >> 6, lane = t & 63;
  const int wm = w >> 2, wn = w & 3;

  // A staging: thread t -> row t>>2 (0..127), k-chunk t&3 (8 floats)
  const int arow = t >> 2;
  const int achk = t & 3;
  int axrow = m0 + arow; if (axrow >= NN) axrow = NN - 1;
  const float* aptr = X + (size_t)axrow * INCH + achk * 8;
  int aidx = (arow >> 4) * 512 + ((arow & 15) + achk * 16) * 8;
  aidx ^= ((aidx >> 7) & 3) << 4;                      // XOR-swizzle (r3: 0 conflicts)
  const int aroff = (lane * 8) ^ (((lane >> 4) & 3) << 4);

  // B global sources: wave w covers n-groups {w, w+8}
  const int bn0 = (w * 16) + (lane & 15);
  const int bko = (lane >> 4) * 8;
  const unsigned short* bs0 = W1Th + (size_t)bn0 * INCH + bko;
  const unsigned short* bs1 = W1Th + (size_t)(bn0 + 128) * INCH + bko;
  const unsigned short* bs2 = W1Tl + (size_t)bn0 * INCH + bko;
  const unsigned short* bs3 = W1Tl + (size_t)(bn0 + 128) * INCH + bko;

  f32x4 acc[4][4] = {};
  float4 rA0[2], rA1[2];   // 2-ahead A register buffers (static-indexed, unrolled)

  // ---- prologue ----
  float4 p0 = *(const float4*)(aptr);              // A(0)
  float4 p1 = *(const float4*)(aptr + 4);
  rA0[1] = *(const float4*)(aptr + 32);            // A(1)
  rA1[1] = *(const float4*)(aptr + 36);
  GLOAD_LDS16(bs0, &Bh[0][w * 512]);               // B(0)
  GLOAD_LDS16(bs1, &Bh[0][(w + 8) * 512]);
  GLOAD_LDS16(bs2, &Bl[0][w * 512]);
  GLOAD_LDS16(bs3, &Bl[0][(w + 8) * 512]);
  PIN();
  WAIT_VM(6);                                      // A(0) regs ready (8 issued, 6 left)
  {
    float af[8] = {p0.x, p0.y, p0.z, p0.w, p1.x, p1.y, p1.z, p1.w};
    short8 ah;
#pragma unroll
    for (int i = 0; i < 8; ++i) {
      unsigned int u = __float_as_uint(af[i]);
      ah[i] = (short)((u + 0x7fffu + ((u >> 16) & 1u)) >> 16);
    }
    *(short8*)&Ah[0][aidx] = ah;
  }

#pragma unroll
  for (int it = 0; it < 16; ++it) {
    const int cur = it & 1, nxt = cur ^ 1;
    // (1) issue next loads: A(it+2) -> regs, B(it+1) -> LDS buf nxt
    if (it < 14) {
      const int ka = (it + 2) * 32;
      if (cur == 0) { rA0[0] = *(const float4*)(aptr + ka); rA1[0] = *(const float4*)(aptr + ka + 4); }
      else          { rA0[1] = *(const float4*)(aptr + ka); rA1[1] = *(const float4*)(aptr + ka + 4); }
    }
    if (it < 15) {
      const int kb = (it + 1) * 32;
      GLOAD_LDS16(bs0 + kb, &Bh[nxt][w * 512]);
      GLOAD_LDS16(bs1 + kb, &Bh[nxt][(w + 8) * 512]);
      GLOAD_LDS16(bs2 + kb, &Bl[nxt][w * 512]);
      GLOAD_LDS16(bs3 + kb, &Bl[nxt][(w + 8) * 512]);
    }
    PIN();
    // (2) counted wait: tile it's B in LDS + A(it+1) regs done; newest loads stay in flight
    if (it < 14)      WAIT_VM(6);
    else if (it == 14) WAIT_VM(4);
    else               WAIT_VM(0);
    PIN();
    // (3) split A(it+1) -> Ah[nxt]
    if (it < 15) {
      float4 qa = (nxt == 0) ? rA0[0] : rA0[1];
      float4 qb = (nxt == 0) ? rA1[0] : rA1[1];
      float af[8] = {qa.x, qa.y, qa.z, qa.w, qb.x, qb.y, qb.z, qb.w};
      short8 ah;
#pragma unroll
      for (int i = 0; i < 8; ++i) {
        unsigned int u = __float_as_uint(af[i]);
        ah[i] = (short)((u + 0x7fffu + ((u >> 16) & 1u)) >> 16);
      }
      *(short8*)&Ah[nxt][aidx] = ah;
    }
    WAIT_LGKM0();
    __builtin_amdgcn_s_barrier();   // publish tile it (B LDS + Ah[cur] from iter it-1)
    PIN();
    // (5) compute tile it
    short8 afrag[4];
#pragma unroll
    for (int mf = 0; mf < 4; ++mf)
      afrag[mf] = *(const short8*)&Ah[cur][(wm * 4 + mf) * 512 + aroff];
#pragma unroll
    for (int nf = 0; nf < 4; ++nf) {
      short8 bfh = *(const short8*)&Bh[cur][(wn * 4 + nf) * 512 + lane * 8];
      short8 bfl = *(const short8*)&Bl[cur][(wn * 4 + nf) * 512 + lane * 8];
#pragma unroll
      for (int mf = 0; mf < 4; ++mf) {
        acc[mf][nf] = __builtin_amdgcn_mfma_f32_16x16x32_bf16(afrag[mf], bfh, acc[mf][nf], 0, 0, 0);
        acc[mf][nf] = __builtin_amdgcn_mfma_f32_16x16x32_bf16(afrag[mf], bfl, acc[mf][nf], 0, 0, 0);
      }
    }
    PIN();
    if (it < 15) {
      __builtin_amdgcn_s_barrier(); // all waves done reading buf cur before overwrite
      PIN();
    }
  }

  // epilogue: +bias, relu, cvt bf16, store
  const int colbase = wn * 64 + (lane & 15);
  const int rowbase = m0 + wm * 64 + ((lane >> 4) << 2);
#pragma unroll
  for (int nf = 0; nf < 4; ++nf) {
    int col = colbase + nf * 16;
    float b = bias1[col];
#pragma unroll
    for (int mf = 0; mf < 4; ++mf) {
#pragma unroll
      for (int r = 0; r < 4; ++r) {
        int row = rowbase + mf * 16 + r;
        if (row < NN) {
          float h = fmaxf(acc[mf][nf][r] + b, 0.f);
          H1bf[(size_t)row * HIDCH + col] = bf16_rne(h);
        }
      }
    }
  }
}

// ---------------- GEMM2: h = H1bf @ W2 + b2 (2-product); hA = h; out = g0*h -------
__global__ __launch_bounds__(256) void k_gemm2(const unsigned short* __restrict__ H1bf,
                                               const unsigned short* __restrict__ W2Th,
                                               const unsigned short* __restrict__ W2Tl,
                                               const float* __restrict__ bias2,
                                               const float* __restrict__ gamma,
                                               float* __restrict__ hA,
                                               float* __restrict__ out) {
  __shared__ __align__(16) unsigned short A2[8192];
  __shared__ __align__(16) unsigned short B2h[2048], B2l[2048];
  const int t = threadIdx.x;
  const int m0 = blockIdx.x * 128;

  const int arow = t >> 1;
  int axrow = m0 + arow; if (axrow >= NN) axrow = NN - 1;
  const int akb = (t & 1) * 32;
  const unsigned short* ap = H1bf + (size_t)axrow * HIDCH + akb;
  const int abase = ((arow >> 4) * 2 + (akb >> 5)) * 512 + (arow & 15) * 8;

  const int bnr = t >> 3, bkq = (t & 7) * 8;
  const int bslot = ((bnr >> 4) * 2 + (bkq >> 5)) * 512 +
                    ((bnr & 15) + (((bkq & 31) >> 3) << 4)) * 8;
  const unsigned short* bhp = W2Th + (size_t)bnr * HIDCH + bkq;
  const unsigned short* blp = W2Tl + (size_t)bnr * HIDCH + bkq;

  const int w = t >> 6, lane = t & 63;

  f32x4 acc[2][2] = {};

  for (int k0 = 0; k0 < HIDCH; k0 += 64) {
    uint4 a0 = *(const uint4*)(ap + k0);
    uint4 a1 = *(const uint4*)(ap + k0 + 8);
    uint4 a2 = *(const uint4*)(ap + k0 + 16);
    uint4 a3 = *(const uint4*)(ap + k0 + 24);
    uint4 bh = *(const uint4*)(bhp + k0);
    uint4 bl = *(const uint4*)(blp + k0);

    __syncthreads();

    *(uint4*)&A2[abase + 0 * 128] = a0;
    *(uint4*)&A2[abase + 1 * 128] = a1;
    *(uint4*)&A2[abase + 2 * 128] = a2;
    *(uint4*)&A2[abase + 3 * 128] = a3;
    *(uint4*)&B2h[bslot] = bh;
    *(uint4*)&B2l[bslot] = bl;

    __syncthreads();

    const short8* AV  = (const short8*)A2;
    const short8* BHV = (const short8*)B2h;
    const short8* BLV = (const short8*)B2l;
#pragma unroll
    for (int k32 = 0; k32 < 2; ++k32) {
      short8 bfh[2], bfl[2];
#pragma unroll
      for (int nf = 0; nf < 2; ++nf) {
        bfh[nf] = BHV[(nf * 2 + k32) * 64 + lane];
        bfl[nf] = BLV[(nf * 2 + k32) * 64 + lane];
      }
#pragma unroll
      for (int mf = 0; mf < 2; ++mf) {
        short8 a = AV[((w * 2 + mf) * 2 + k32) * 64 + lane];
#pragma unroll
        for (int nf = 0; nf < 2; ++nf) {
          acc[mf][nf] = __builtin_amdgcn_mfma_f32_16x16x32_bf16(a, bfh[nf], acc[mf][nf], 0, 0, 0);
          acc[mf][nf] = __builtin_amdgcn_mfma_f32_16x16x32_bf16(a, bfl[nf], acc[mf][nf], 0, 0, 0);
        }
      }
    }
  }

  const float g0 = gamma[0];
  const int colb = lane & 15;
  const int rowb = m0 + w * 32 + ((lane >> 4) << 2);
#pragma unroll
  for (int nf = 0; nf < 2; ++nf) {
    int col = nf * 16 + colb;
    float b = bias2[col];
#pragma unroll
    for (int mf = 0; mf < 2; ++mf) {
#pragma unroll
      for (int r = 0; r < 4; ++r) {
        int row = rowb + mf * 16 + r;
        if (row < NN) {
          float h = acc[mf][nf][r] + b;
          hA[(size_t)row * OUTCH + col] = h;
          out[(size_t)row * OUTCH + col] = g0 * h;
        }
      }
    }
  }
}

// ---------------- one propagation hop + gamma accumulation ----------------
// 16 nodes/block, quarter-wave (16 lanes x float2 = 32 ch) per node.
// One gather instruction serves 4 nodes' edges; meta rows bank-staggered.
__global__ __launch_bounds__(256) void k_hop(const float* __restrict__ hin,
                                             float* __restrict__ hout,
                                             float* __restrict__ out,
                                             const int* __restrict__ rp,
                                             const int2* __restrict__ epk,
                                             const float* __restrict__ gamma,
                                             int k) {
  __shared__ int2 meta[16][20];   // row stride 160B: quarters hit disjoint banks
  const int t = threadIdx.x;
  const int q = t >> 4;           // node slot 0..15
  const int c2 = t & 15;          // channel pair 0..15
  const int v = blockIdx.x * 16 + q;
  const int s = rp[v], e = rp[v + 1];
  float ax0 = 0.f, ay0 = 0.f, ax1 = 0.f, ay1 = 0.f;
  float ax2 = 0.f, ay2 = 0.f, ax3 = 0.f, ay3 = 0.f;
  for (int base = s; base < e; base += 16) {
    const int cnt = min(16, e - base);
    int2 m = (c2 < cnt) ? epk[base + c2] : make_int2(0, 0);  // pad: src 0, norm 0
    meta[q][c2] = m;               // same-wave producer/consumer: lgkmcnt only
    const int steps = (cnt + 3) >> 2;
    for (int j = 0; j < steps; ++j) {
      int4 e01 = *(const int4*)&meta[q][j * 4];
      int4 e23 = *(const int4*)&meta[q][j * 4 + 2];
      float2 g0 = *(const float2*)&hin[(size_t)e01.x * OUTCH + c2 * 2];
      float2 g1 = *(const float2*)&hin[(size_t)e01.z * OUTCH + c2 * 2];
      float2 g2 = *(const float2*)&hin[(size_t)e23.x * OUTCH + c2 * 2];
      float2 g3 = *(const float2*)&hin[(size_t)e23.z * OUTCH + c2 * 2];
      float n0 = __int_as_float(e01.y), n1 = __int_as_float(e01.w);
      float n2 = __int_as_float(e23.y), n3 = __int_as_float(e23.w);
      ax0 = fmaf(n0, g0.x, ax0); ay0 = fmaf(n0, g0.y, ay0);
      ax1 = fmaf(n1, g1.x, ax1); ay1 = fmaf(n1, g1.y, ay1);
      ax2 = fmaf(n2, g2.x, ax2); ay2 = fmaf(n2, g2.y, ay2);
      ax3 = fmaf(n3, g3.x, ax3); ay3 = fmaf(n3, g3.y, ay3);
    }
  }
  const float tx = (ax0 + ax1) + (ax2 + ax3);
  const float ty = (ay0 + ay1) + (ay2 + ay3);
  const size_t o = (size_t)v * OUTCH + c2 * 2;
  *(float2*)&hout[o] = make_float2(tx, ty);
  const float g = gamma[k];
  float2 po = *(const float2*)&out[o];
  *(float2*)&out[o] = make_float2(fmaf(g, tx, po.x), fmaf(g, ty, po.y));
}

extern "C" void kernel_launch(void* const* d_in, const int* in_sizes, int n_in,
                              void* d_out, int out_size, void* d_ws, size_t ws_size,
                              hipStream_t stream) {
  const float* x     = (const float*)d_in[0];
  const int*   ei    = (const int*)d_in[1];
  const float* W1    = (const float*)d_in[2];
  const float* b1    = (const float*)d_in[3];
  const float* W2    = (const float*)d_in[4];
  const float* b2    = (const float*)d_in[5];
  const float* gamma = (const float*)d_in[6];
  float* out = (float*)d_out;

  char* ws = (char*)d_ws;
  unsigned short* h1bf = (unsigned short*)(ws + OFF_H1);
  float* hA   = (float*)(ws + OFF_HA);
  float* hB   = (float*)(ws + OFF_HB);
  unsigned short* w1th = (unsigned short*)(ws + OFF_W1TH);
  unsigned short* w1tl = (unsigned short*)(ws + OFF_W1TL);
  unsigned short* w2th = (unsigned short*)(ws + OFF_W2TH);
  unsigned short* w2tl = (unsigned short*)(ws + OFF_W2TL);
  int*   deg  = (int*)(ws + OFF_DEG);
  float* dis  = (float*)(ws + OFF_DIS);
  int*   rp   = (int*)(ws + OFF_RP);
  int*   cur  = (int*)(ws + OFF_CUR);
  int2*  epk  = (int2*)(ws + OFF_EPK);
  int*   part = (int*)(ws + OFF_PART);
  int*   offs = (int*)(ws + OFF_OFFS);

  hipMemsetAsync(deg, 0, NN * sizeof(int), stream);

  // weight prep (tiny)
  k_splitT<<<(INCH * HIDCH + 255) / 256, 256, 0, stream>>>(W1, w1th, w1tl, INCH, HIDCH);
  k_splitT<<<(HIDCH * OUTCH + 255) / 256, 256, 0, stream>>>(W2, w2th, w2tl, HIDCH, OUTCH);

  // graph prep
  k_count_deg<<<(NE + 255) / 256, 256, 0, stream>>>(ei + NE, deg);
  k_dis<<<(NN + 255) / 256, 256, 0, stream>>>(deg, dis);
  k_scan1<<<98, 256, 0, stream>>>(deg, rp, part);
  k_scan2<<<1, 128, 0, stream>>>(part, offs);
  k_scan3<<<98, 256, 0, stream>>>(rp, offs, cur);
  k_fill<<<(NE + 255) / 256, 256, 0, stream>>>(ei, dis, cur, epk);

  // MLP
  k_gemm1<<<(NN + 127) / 128, 512, 0, stream>>>(x, w1th, w1tl, b1, h1bf);
  k_gemm2<<<(NN + 127) / 128, 256, 0, stream>>>(h1bf, w2th, w2tl, b2, gamma, hA, out);

  // propagation
  float* hin = hA;
  float* hout = hB;
  for (int k = 1; k <= KHOPS; ++k) {
    k_hop<<<NN / 16, 256, 0, stream>>>(hin, hout, out, rp, epk, gamma, k);
    float* tmp = hin; hin = hout; hout = tmp;
  }
}

// Round 6
// 645.237 us; speedup vs baseline: 1.0336x; 1.0336x over previous
//
#include <hip/hip_runtime.h>
#include <hip/hip_bf16.h>

#define NN    100000
#define NE    1600000
#define INCH  512
#define HIDCH 256
#define OUTCH 32
#define KHOPS 10
#define NEPAD (NE + 3 * NN)

typedef __attribute__((ext_vector_type(8))) short short8;
typedef __attribute__((ext_vector_type(4))) float f32x4;

#define GLOAD_LDS16(gsrc, ldst) \
  __builtin_amdgcn_global_load_lds((const __attribute__((address_space(1))) void*)(gsrc), \
                                   (__attribute__((address_space(3))) void*)(ldst), 16, 0, 0)

// ---------------- workspace layout ----------------
constexpr size_t ws_align(size_t x) { return (x + 255) & ~(size_t)255; }
constexpr size_t USZ = ws_align((size_t)(NN + 1) * 16 * 2);   // half-table bf16 (+pad row)
constexpr size_t OSZ = ws_align((size_t)NN * 16 * 4);         // oacc half f32
constexpr size_t OFF_H1   = 0;                                           // [NN][256] bf16
constexpr size_t OFF_U00  = OFF_H1   + ws_align((size_t)NN*HIDCH*2);     // parity0 half0
constexpr size_t OFF_U01  = OFF_U00  + USZ;                              // parity0 half1
constexpr size_t OFF_U10  = OFF_U01  + USZ;                              // parity1 half0
constexpr size_t OFF_U11  = OFF_U10  + USZ;                              // parity1 half1
constexpr size_t OFF_OA0  = OFF_U11  + USZ;
constexpr size_t OFF_OA1  = OFF_OA0  + OSZ;
constexpr size_t OFF_W1TH = OFF_OA1  + OSZ;                              // [256][512] bf16
constexpr size_t OFF_W1TL = OFF_W1TH + ws_align((size_t)HIDCH*INCH*2);
constexpr size_t OFF_W2TH = OFF_W1TL + ws_align((size_t)HIDCH*INCH*2);   // [32][256] bf16
constexpr size_t OFF_W2TL = OFF_W2TH + ws_align((size_t)OUTCH*HIDCH*2);
constexpr size_t OFF_DEG  = OFF_W2TL + ws_align((size_t)OUTCH*HIDCH*2);  // [NN] int
constexpr size_t OFF_DIS  = OFF_DEG  + ws_align((size_t)NN*4);           // [NN] f32
constexpr size_t OFF_RP   = OFF_DIS  + ws_align((size_t)NN*4);           // [NN+1] int (deg rounded to 4)
constexpr size_t OFF_CUR  = OFF_RP   + ws_align((size_t)(NN+1)*4);       // [NN] int
constexpr size_t OFF_CSR  = OFF_CUR  + ws_align((size_t)NN*4);           // [NEPAD] int src
constexpr size_t OFF_PART = OFF_CSR  + ws_align((size_t)NEPAD*4);        // [128] int
constexpr size_t OFF_OFFS = OFF_PART + ws_align(512);                    // [128] int

// ---------------- bf16 helpers ----------------
__device__ __forceinline__ unsigned short bf16_rne(float f) {
  unsigned int u = __float_as_uint(f);
  u += 0x7fffu + ((u >> 16) & 1u);
  return (unsigned short)(u >> 16);
}
__device__ __forceinline__ float bf16_to_f32(unsigned short h) {
  return __uint_as_float(((unsigned int)h) << 16);
}

// ---------------- degree ----------------
__global__ __launch_bounds__(256) void k_count_deg(const int* __restrict__ col,
                                                   int* __restrict__ deg) {
  int e = blockIdx.x * 256 + threadIdx.x;
  if (e < NE) atomicAdd(&deg[col[e]], 1);
}

// dis + zero the 4 U pad rows (row NN of each half-table)
__global__ __launch_bounds__(256) void k_dis(const int* __restrict__ deg,
                                             float* __restrict__ dis,
                                             unsigned short* u00, unsigned short* u01,
                                             unsigned short* u10, unsigned short* u11) {
  int v = blockIdx.x * 256 + threadIdx.x;
  if (v < NN) {
    int d = deg[v];
    dis[v] = d > 0 ? rsqrtf((float)d) : 0.0f;
  }
  if (blockIdx.x == 0) {
    int t = threadIdx.x;
    if (t < 8)       ((unsigned int*)u00)[(size_t)NN * 8 + t] = 0;
    else if (t < 16) ((unsigned int*)u01)[(size_t)NN * 8 + (t - 8)] = 0;
    else if (t < 24) ((unsigned int*)u10)[(size_t)NN * 8 + (t - 16)] = 0;
    else if (t < 32) ((unsigned int*)u11)[(size_t)NN * 8 + (t - 24)] = 0;
  }
}

// ---------------- exclusive scan over deg rounded-up-to-4 ----------------
__global__ __launch_bounds__(256) void k_scan1(const int* __restrict__ deg,
                                               int* __restrict__ rp,
                                               int* __restrict__ part) {
  __shared__ int s[256];
  int b = blockIdx.x, t = threadIdx.x;
  int base = b * 1024 + t * 4;
  int v0 = (base + 0 < NN) ? ((deg[base + 0] + 3) & ~3) : 0;
  int v1 = (base + 1 < NN) ? ((deg[base + 1] + 3) & ~3) : 0;
  int v2 = (base + 2 < NN) ? ((deg[base + 2] + 3) & ~3) : 0;
  int v3 = (base + 3 < NN) ? ((deg[base + 3] + 3) & ~3) : 0;
  int tot = v0 + v1 + v2 + v3;
  s[t] = tot;
  __syncthreads();
  for (int d = 1; d < 256; d <<= 1) {
    int x = (t >= d) ? s[t - d] : 0;
    __syncthreads();
    s[t] += x;
    __syncthreads();
  }
  int excl = s[t] - tot;
  if (t == 255) part[b] = s[255];
  if (base + 0 < NN) rp[base + 0] = excl;
  if (base + 1 < NN) rp[base + 1] = excl + v0;
  if (base + 2 < NN) rp[base + 2] = excl + v0 + v1;
  if (base + 3 < NN) rp[base + 3] = excl + v0 + v1 + v2;
}

__global__ __launch_bounds__(128) void k_scan2(const int* __restrict__ part,
                                               int* __restrict__ offs) {
  __shared__ int s[128];
  int t = threadIdx.x;
  int v = (t < 98) ? part[t] : 0;
  s[t] = v;
  __syncthreads();
  for (int d = 1; d < 128; d <<= 1) {
    int x = (t >= d) ? s[t - d] : 0;
    __syncthreads();
    s[t] += x;
    __syncthreads();
  }
  if (t < 98) offs[t] = s[t] - v;
}

__global__ __launch_bounds__(256) void k_scan3(int* __restrict__ rp,
                                               const int* __restrict__ offs,
                                               const int* __restrict__ part,
                                               int* __restrict__ cur) {
  int b = blockIdx.x, t = threadIdx.x;
  int o = offs[b];
  int base = b * 1024 + t * 4;
#pragma unroll
  for (int j = 0; j < 4; ++j) {
    int i = base + j;
    if (i < NN) {
      int r = rp[i] + o;
      rp[i] = r;
      cur[i] = r;
    }
  }
  if (b == 0 && t == 0) rp[NN] = offs[97] + part[97];
}

// fill CSR src-only
__global__ __launch_bounds__(256) void k_fill(const int* __restrict__ ei,
                                              int* __restrict__ cur,
                                              int* __restrict__ csrc) {
  int e = blockIdx.x * 256 + threadIdx.x;
  if (e < NE) {
    int c = ei[NE + e];
    int p = atomicAdd(&cur[c], 1);
    csrc[p] = ei[e];
  }
}

// pad each node's slots up to rounded length with dummy src = NN (zero row)
__global__ __launch_bounds__(256) void k_pad(const int* __restrict__ cur,
                                             const int* __restrict__ rp,
                                             int* __restrict__ csrc) {
  int v = blockIdx.x * 256 + threadIdx.x;
  if (v < NN) {
    int p = cur[v], e = rp[v + 1];
    for (; p < e; ++p) csrc[p] = NN;
  }
}

// ---------------- split-transpose: dst[n][k] = split(src[k][n]) ----------------
__global__ __launch_bounds__(256) void k_splitT(const float* __restrict__ src,
                                                unsigned short* __restrict__ dh,
                                                unsigned short* __restrict__ dl,
                                                int K, int N) {
  int idx = blockIdx.x * 256 + threadIdx.x;
  if (idx >= K * N) return;
  int n = idx / K, k = idx - n * K;
  float v = src[(size_t)k * N + n];
  unsigned short h = bf16_rne(v);
  dh[idx] = h;
  dl[idx] = bf16_rne(v - bf16_to_f32(h));
}

// ---------------- GEMM1 (r4 structure, unchanged): H1bf = bf16(relu(X@W1+b1)) ----
__global__ __launch_bounds__(512, 2) void k_gemm1(const float* __restrict__ X,
                                                  const unsigned short* __restrict__ W1Th,
                                                  const unsigned short* __restrict__ W1Tl,
                                                  const float* __restrict__ bias1,
                                                  unsigned short* __restrict__ H1bf) {
  __shared__ __align__(16) unsigned short Ah[2][4096];
  __shared__ __align__(16) unsigned short Bh[2][8192], Bl[2][8192];
  const int t = threadIdx.x;
  const int m0 = blockIdx.x * 128;
  const int w = t >> 6, lane = t & 63;
  const int wm = w >> 2, wn = w & 3;

  const int arow = t >> 2;
  const int achk = t & 3;
  int axrow = m0 + arow; if (axrow >= NN) axrow = NN - 1;
  const float* aptr = X + (size_t)axrow * INCH + achk * 8;
  int aidx = (arow >> 4) * 512 + ((arow & 15) + achk * 16) * 8;
  aidx ^= ((aidx >> 7) & 3) << 4;
  const int aroff = (lane * 8) ^ (((lane >> 4) & 3) << 4);

  const int bn0 = (w * 16) + (lane & 15);
  const int bko = (lane >> 4) * 8;
  const unsigned short* bs0 = W1Th + (size_t)bn0 * INCH + bko;
  const unsigned short* bs1 = W1Th + (size_t)(bn0 + 128) * INCH + bko;
  const unsigned short* bs2 = W1Tl + (size_t)bn0 * INCH + bko;
  const unsigned short* bs3 = W1Tl + (size_t)(bn0 + 128) * INCH + bko;

  f32x4 acc[4][4] = {};
  float4 av0, av1;

  av0 = *(const float4*)(aptr);
  av1 = *(const float4*)(aptr + 4);
  GLOAD_LDS16(bs0, &Bh[0][w * 512]);
  GLOAD_LDS16(bs1, &Bh[0][(w + 8) * 512]);
  GLOAD_LDS16(bs2, &Bl[0][w * 512]);
  GLOAD_LDS16(bs3, &Bl[0][(w + 8) * 512]);
  {
    float af[8] = {av0.x, av0.y, av0.z, av0.w, av1.x, av1.y, av1.z, av1.w};
    short8 ah;
#pragma unroll
    for (int i = 0; i < 8; ++i) {
      unsigned int u = __float_as_uint(af[i]);
      ah[i] = (short)((u + 0x7fffu + ((u >> 16) & 1u)) >> 16);
    }
    *(short8*)&Ah[0][aidx] = ah;
  }
  __syncthreads();

#pragma unroll
  for (int it = 0; it < 16; ++it) {
    const int cur = it & 1, nxt = cur ^ 1;
    const int k0 = it * 32;
    if (it < 15) {
      av0 = *(const float4*)(aptr + k0 + 32);
      av1 = *(const float4*)(aptr + k0 + 36);
      GLOAD_LDS16(bs0 + k0 + 32, &Bh[nxt][w * 512]);
      GLOAD_LDS16(bs1 + k0 + 32, &Bh[nxt][(w + 8) * 512]);
      GLOAD_LDS16(bs2 + k0 + 32, &Bl[nxt][w * 512]);
      GLOAD_LDS16(bs3 + k0 + 32, &Bl[nxt][(w + 8) * 512]);
    }
    short8 afrag[4];
#pragma unroll
    for (int mf = 0; mf < 4; ++mf)
      afrag[mf] = *(const short8*)&Ah[cur][(wm * 4 + mf) * 512 + aroff];
#pragma unroll
    for (int nf = 0; nf < 4; ++nf) {
      short8 bfh = *(const short8*)&Bh[cur][(wn * 4 + nf) * 512 + lane * 8];
      short8 bfl = *(const short8*)&Bl[cur][(wn * 4 + nf) * 512 + lane * 8];
#pragma unroll
      for (int mf = 0; mf < 4; ++mf) {
        acc[mf][nf] = __builtin_amdgcn_mfma_f32_16x16x32_bf16(afrag[mf], bfh, acc[mf][nf], 0, 0, 0);
        acc[mf][nf] = __builtin_amdgcn_mfma_f32_16x16x32_bf16(afrag[mf], bfl, acc[mf][nf], 0, 0, 0);
      }
    }
    if (it < 15) {
      float af[8] = {av0.x, av0.y, av0.z, av0.w, av1.x, av1.y, av1.z, av1.w};
      short8 ah;
#pragma unroll
      for (int i = 0; i < 8; ++i) {
        unsigned int u = __float_as_uint(af[i]);
        ah[i] = (short)((u + 0x7fffu + ((u >> 16) & 1u)) >> 16);
      }
      *(short8*)&Ah[nxt][aidx] = ah;
    }
    __syncthreads();
  }

  const int colbase = wn * 64 + (lane & 15);
  const int rowbase = m0 + wm * 64 + ((lane >> 4) << 2);
#pragma unroll
  for (int nf = 0; nf < 4; ++nf) {
    int col = colbase + nf * 16;
    float b = bias1[col];
#pragma unroll
    for (int mf = 0; mf < 4; ++mf) {
#pragma unroll
      for (int r = 0; r < 4; ++r) {
        int row = rowbase + mf * 16 + r;
        if (row < NN) {
          float h = fmaxf(acc[mf][nf][r] + b, 0.f);
          H1bf[(size_t)row * HIDCH + col] = bf16_rne(h);
        }
      }
    }
  }
}

// ---------------- GEMM2: h = H1bf @ W2 + b2; write u0 halves + oacc init ----------
__global__ __launch_bounds__(256) void k_gemm2(const unsigned short* __restrict__ H1bf,
                                               const unsigned short* __restrict__ W2Th,
                                               const unsigned short* __restrict__ W2Tl,
                                               const float* __restrict__ bias2,
                                               const float* __restrict__ gamma,
                                               const float* __restrict__ dis,
                                               unsigned short* __restrict__ u00,
                                               unsigned short* __restrict__ u01,
                                               float* __restrict__ oa0,
                                               float* __restrict__ oa1) {
  __shared__ __align__(16) unsigned short A2[8192];
  __shared__ __align__(16) unsigned short B2h[2048], B2l[2048];
  const int t = threadIdx.x;
  const int m0 = blockIdx.x * 128;

  const int arow = t >> 1;
  int axrow = m0 + arow; if (axrow >= NN) axrow = NN - 1;
  const int akb = (t & 1) * 32;
  const unsigned short* ap = H1bf + (size_t)axrow * HIDCH + akb;
  const int abase = ((arow >> 4) * 2 + (akb >> 5)) * 512 + (arow & 15) * 8;

  const int bnr = t >> 3, bkq = (t & 7) * 8;
  const int bslot = ((bnr >> 4) * 2 + (bkq >> 5)) * 512 +
                    ((bnr & 15) + (((bkq & 31) >> 3) << 4)) * 8;
  const unsigned short* bhp = W2Th + (size_t)bnr * HIDCH + bkq;
  const unsigned short* blp = W2Tl + (size_t)bnr * HIDCH + bkq;

  const int w = t >> 6, lane = t & 63;

  f32x4 acc[2][2] = {};

  for (int k0 = 0; k0 < HIDCH; k0 += 64) {
    uint4 a0 = *(const uint4*)(ap + k0);
    uint4 a1 = *(const uint4*)(ap + k0 + 8);
    uint4 a2 = *(const uint4*)(ap + k0 + 16);
    uint4 a3 = *(const uint4*)(ap + k0 + 24);
    uint4 bh = *(const uint4*)(bhp + k0);
    uint4 bl = *(const uint4*)(blp + k0);

    __syncthreads();

    *(uint4*)&A2[abase + 0 * 128] = a0;
    *(uint4*)&A2[abase + 1 * 128] = a1;
    *(uint4*)&A2[abase + 2 * 128] = a2;
    *(uint4*)&A2[abase + 3 * 128] = a3;
    *(uint4*)&B2h[bslot] = bh;
    *(uint4*)&B2l[bslot] = bl;

    __syncthreads();

    const short8* AV  = (const short8*)A2;
    const short8* BHV = (const short8*)B2h;
    const short8* BLV = (const short8*)B2l;
#pragma unroll
    for (int k32 = 0; k32 < 2; ++k32) {
      short8 bfh[2], bfl[2];
#pragma unroll
      for (int nf = 0; nf < 2; ++nf) {
        bfh[nf] = BHV[(nf * 2 + k32) * 64 + lane];
        bfl[nf] = BLV[(nf * 2 + k32) * 64 + lane];
      }
#pragma unroll
      for (int mf = 0; mf < 2; ++mf) {
        short8 a = AV[((w * 2 + mf) * 2 + k32) * 64 + lane];
#pragma unroll
        for (int nf = 0; nf < 2; ++nf) {
          acc[mf][nf] = __builtin_amdgcn_mfma_f32_16x16x32_bf16(a, bfh[nf], acc[mf][nf], 0, 0, 0);
          acc[mf][nf] = __builtin_amdgcn_mfma_f32_16x16x32_bf16(a, bfl[nf], acc[mf][nf], 0, 0, 0);
        }
      }
    }
  }

  const float g0 = gamma[0];
  const int colb = lane & 15;
  const int rowb = m0 + w * 32 + ((lane >> 4) << 2);
  const float b2c0 = bias2[colb], b2c1 = bias2[16 + colb];
#pragma unroll
  for (int mf = 0; mf < 2; ++mf) {
#pragma unroll
    for (int r = 0; r < 4; ++r) {
      int row = rowb + mf * 16 + r;
      if (row < NN) {
        float dv = dis[row];
        float h0 = acc[mf][0][r] + b2c0;
        float h1 = acc[mf][1][r] + b2c1;
        size_t o = (size_t)row * 16 + colb;
        u00[o] = bf16_rne(dv * h0);
        u01[o] = bf16_rne(dv * h1);
        oa0[o] = g0 * h0;
        oa1[o] = g0 * h1;
      }
    }
  }
}

// ---------------- hop half-pass: Uout[v] = dis(v)^2 * S, oacc += gamma*dis*S ------
// 8-lane group per node (16 ch bf16 = 32B row); 32 nodes/block.
// Meta: padded CSR (deg%4==0, pads -> src NN = zero row), aligned int4 loads.
__global__ __launch_bounds__(256) void k_hop(const unsigned short* __restrict__ Uin,
                                             unsigned short* __restrict__ Uout,
                                             float* __restrict__ oacc,
                                             const int* __restrict__ rp,
                                             const int* __restrict__ csrc,
                                             const float* __restrict__ dis,
                                             const float* __restrict__ gamma,
                                             int k) {
  __shared__ int meta[32][36];   // 32 groups x 32 edges (+4 pad ints: bank stagger)
  const int t = threadIdx.x;
  const int g = t >> 3;          // group 0..31
  const int li = t & 7;          // lane in group
  const int v = blockIdx.x * 32 + g;
  const int s = rp[v], e = rp[v + 1];
  float ax0 = 0.f, ay0 = 0.f, ax1 = 0.f, ay1 = 0.f;
  float ax2 = 0.f, ay2 = 0.f, ax3 = 0.f, ay3 = 0.f;
  for (int base = s; base < e; base += 32) {
    const int idx0 = base + li * 4;
    int4 mv = make_int4(NN, NN, NN, NN);
    if (idx0 < e) mv = *(const int4*)&csrc[idx0];   // aligned: rp mult of 4
    *(int4*)&meta[g][li * 4] = mv;
    const int cnt = min(32, e - base);              // mult of 4
    const int nst = cnt >> 2;
    for (int j = 0; j < nst; ++j) {
      int4 sv = *(const int4*)&meta[g][j * 4];      // uniform in group
      unsigned int w0 = *(const unsigned int*)&Uin[(size_t)sv.x * 16 + li * 2];
      unsigned int w1 = *(const unsigned int*)&Uin[(size_t)sv.y * 16 + li * 2];
      unsigned int w2 = *(const unsigned int*)&Uin[(size_t)sv.z * 16 + li * 2];
      unsigned int w3 = *(const unsigned int*)&Uin[(size_t)sv.w * 16 + li * 2];
      ax0 += __uint_as_float(w0 << 16); ay0 += __uint_as_float(w0 & 0xffff0000u);
      ax1 += __uint_as_float(w1 << 16); ay1 += __uint_as_float(w1 & 0xffff0000u);
      ax2 += __uint_as_float(w2 << 16); ay2 += __uint_as_float(w2 & 0xffff0000u);
      ax3 += __uint_as_float(w3 << 16); ay3 += __uint_as_float(w3 & 0xffff0000u);
    }
  }
  const float Sx = (ax0 + ax1) + (ax2 + ax3);
  const float Sy = (ay0 + ay1) + (ay2 + ay3);
  const float dv = dis[v];
  const float gd = gamma[k] * dv;
  const float d2 = dv * dv;
  unsigned int packed = (unsigned int)bf16_rne(d2 * Sx) |
                        ((unsigned int)bf16_rne(d2 * Sy) << 16);
  ((unsigned int*)Uout)[(size_t)v * 8 + li] = packed;
  float2 po = *(const float2*)&oacc[(size_t)v * 16 + li * 2];
  po.x = fmaf(gd, Sx, po.x);
  po.y = fmaf(gd, Sy, po.y);
  *(float2*)&oacc[(size_t)v * 16 + li * 2] = po;
}

// ---------------- merge oacc halves -> out [NN][32] ----------------
__global__ __launch_bounds__(256) void k_merge(const float* __restrict__ oa0,
                                               const float* __restrict__ oa1,
                                               float* __restrict__ out) {
  int i4 = blockIdx.x * 256 + threadIdx.x;          // float4 index, NN*8 total
  if (i4 >= NN * 8) return;
  int v = i4 >> 3;
  int j = (i4 & 7) * 4;                              // 0,4,...,28
  const float* src = (j < 16) ? oa0 : oa1;
  float4 val = *(const float4*)&src[(size_t)v * 16 + (j & 15)];
  *(float4*)&out[(size_t)v * 32 + j] = val;
}

extern "C" void kernel_launch(void* const* d_in, const int* in_sizes, int n_in,
                              void* d_out, int out_size, void* d_ws, size_t ws_size,
                              hipStream_t stream) {
  const float* x     = (const float*)d_in[0];
  const int*   ei    = (const int*)d_in[1];
  const float* W1    = (const float*)d_in[2];
  const float* b1    = (const float*)d_in[3];
  const float* W2    = (const float*)d_in[4];
  const float* b2    = (const float*)d_in[5];
  const float* gamma = (const float*)d_in[6];
  float* out = (float*)d_out;

  char* ws = (char*)d_ws;
  unsigned short* h1bf = (unsigned short*)(ws + OFF_H1);
  unsigned short* U[2][2] = {
    {(unsigned short*)(ws + OFF_U00), (unsigned short*)(ws + OFF_U01)},
    {(unsigned short*)(ws + OFF_U10), (unsigned short*)(ws + OFF_U11)}};
  float* oa0 = (float*)(ws + OFF_OA0);
  float* oa1 = (float*)(ws + OFF_OA1);
  unsigned short* w1th = (unsigned short*)(ws + OFF_W1TH);
  unsigned short* w1tl = (unsigned short*)(ws + OFF_W1TL);
  unsigned short* w2th = (unsigned short*)(ws + OFF_W2TH);
  unsigned short* w2tl = (unsigned short*)(ws + OFF_W2TL);
  int*   deg  = (int*)(ws + OFF_DEG);
  float* dis  = (float*)(ws + OFF_DIS);
  int*   rp   = (int*)(ws + OFF_RP);
  int*   cur  = (int*)(ws + OFF_CUR);
  int*   csrc = (int*)(ws + OFF_CSR);
  int*   part = (int*)(ws + OFF_PART);
  int*   offs = (int*)(ws + OFF_OFFS);

  hipMemsetAsync(deg, 0, NN * sizeof(int), stream);

  // weight prep (tiny)
  k_splitT<<<(INCH * HIDCH + 255) / 256, 256, 0, stream>>>(W1, w1th, w1tl, INCH, HIDCH);
  k_splitT<<<(HIDCH * OUTCH + 255) / 256, 256, 0, stream>>>(W2, w2th, w2tl, HIDCH, OUTCH);

  // graph prep
  k_count_deg<<<(NE + 255) / 256, 256, 0, stream>>>(ei + NE, deg);
  k_dis<<<(NN + 255) / 256, 256, 0, stream>>>(deg, dis, U[0][0], U[0][1], U[1][0], U[1][1]);
  k_scan1<<<98, 256, 0, stream>>>(deg, rp, part);
  k_scan2<<<1, 128, 0, stream>>>(part, offs);
  k_scan3<<<98, 256, 0, stream>>>(rp, offs, part, cur);
  k_fill<<<(NE + 255) / 256, 256, 0, stream>>>(ei, cur, csrc);
  k_pad<<<(NN + 255) / 256, 256, 0, stream>>>(cur, rp, csrc);

  // MLP
  k_gemm1<<<(NN + 127) / 128, 512, 0, stream>>>(x, w1th, w1tl, b1, h1bf);
  k_gemm2<<<(NN + 127) / 128, 256, 0, stream>>>(h1bf, w2th, w2tl, b2, gamma, dis,
                                                U[0][0], U[0][1], oa0, oa1);

  // propagation: 10 hops x 2 channel-halves (half-table L2-resident)
  for (int k = 1; k <= KHOPS; ++k) {
    const int pin = (k - 1) & 1, pout = k & 1;
    k_hop<<<NN / 32, 256, 0, stream>>>(U[pin][0], U[pout][0], oa0, rp, csrc, dis, gamma, k);
    k_hop<<<NN / 32, 256, 0, stream>>>(U[pin][1], U[pout][1], oa1, rp, csrc, dis, gamma, k);
  }

  k_merge<<<(NN * 8 + 255) / 256, 256, 0, stream>>>(oa0, oa1, out);
}

// Round 7
// 606.879 us; speedup vs baseline: 1.0990x; 1.0632x over previous
//
#include <hip/hip_runtime.h>
#include <hip/hip_bf16.h>

#define NN    100000
#define NE    1600000
#define INCH  512
#define HIDCH 256
#define OUTCH 32
#define KHOPS 10
#define NEPAD (NE + 3 * NN)

typedef __attribute__((ext_vector_type(8))) short short8;
typedef __attribute__((ext_vector_type(4))) float f32x4;

#define GLOAD_LDS16(gsrc, ldst) \
  __builtin_amdgcn_global_load_lds((const __attribute__((address_space(1))) void*)(gsrc), \
                                   (__attribute__((address_space(3))) void*)(ldst), 16, 0, 0)

// ---------------- workspace layout ----------------
constexpr size_t ws_align(size_t x) { return (x + 255) & ~(size_t)255; }
constexpr size_t USZ = ws_align((size_t)(NN + 1) * 16 * 2);   // half-table bf16 (+pad row)
constexpr size_t OSZ = ws_align((size_t)NN * 16 * 4);         // oacc half f32
constexpr size_t OFF_H1   = 0;                                           // [NN][256] bf16
constexpr size_t OFF_U00  = OFF_H1   + ws_align((size_t)NN*HIDCH*2);     // parity0 half0
constexpr size_t OFF_U01  = OFF_U00  + USZ;                              // parity0 half1
constexpr size_t OFF_U10  = OFF_U01  + USZ;                              // parity1 half0
constexpr size_t OFF_U11  = OFF_U10  + USZ;                              // parity1 half1
constexpr size_t OFF_OA0  = OFF_U11  + USZ;
constexpr size_t OFF_OA1  = OFF_OA0  + OSZ;
constexpr size_t OFF_W1TH = OFF_OA1  + OSZ;                              // [256][512] bf16
constexpr size_t OFF_W1TL = OFF_W1TH + ws_align((size_t)HIDCH*INCH*2);
constexpr size_t OFF_W2TH = OFF_W1TL + ws_align((size_t)HIDCH*INCH*2);   // [32][256] bf16
constexpr size_t OFF_W2TL = OFF_W2TH + ws_align((size_t)OUTCH*HIDCH*2);
constexpr size_t OFF_DEG  = OFF_W2TL + ws_align((size_t)OUTCH*HIDCH*2);  // [NN] int
constexpr size_t OFF_DIS  = OFF_DEG  + ws_align((size_t)NN*4);           // [NN] f32
constexpr size_t OFF_RP   = OFF_DIS  + ws_align((size_t)NN*4);           // [NN+1] int (deg rounded to 4)
constexpr size_t OFF_CUR  = OFF_RP   + ws_align((size_t)(NN+1)*4);       // [NN] int
constexpr size_t OFF_CSR  = OFF_CUR  + ws_align((size_t)NN*4);           // [NEPAD] int src
constexpr size_t OFF_PART = OFF_CSR  + ws_align((size_t)NEPAD*4);        // [128] int
constexpr size_t OFF_OFFS = OFF_PART + ws_align(512);                    // [128] int

// ---------------- bf16 helpers ----------------
__device__ __forceinline__ unsigned short bf16_rne(float f) {
  unsigned int u = __float_as_uint(f);
  u += 0x7fffu + ((u >> 16) & 1u);
  return (unsigned short)(u >> 16);
}
__device__ __forceinline__ float bf16_to_f32(unsigned short h) {
  return __uint_as_float(((unsigned int)h) << 16);
}
__device__ __forceinline__ float bflo(unsigned int w) {
  return __uint_as_float(w << 16);
}
__device__ __forceinline__ float bfhi(unsigned int w) {
  return __uint_as_float(w & 0xffff0000u);
}

// ---------------- degree ----------------
__global__ __launch_bounds__(256) void k_count_deg(const int* __restrict__ col,
                                                   int* __restrict__ deg) {
  int e = blockIdx.x * 256 + threadIdx.x;
  if (e < NE) atomicAdd(&deg[col[e]], 1);
}

// dis + zero the 4 U pad rows (row NN of each half-table)
__global__ __launch_bounds__(256) void k_dis(const int* __restrict__ deg,
                                             float* __restrict__ dis,
                                             unsigned short* u00, unsigned short* u01,
                                             unsigned short* u10, unsigned short* u11) {
  int v = blockIdx.x * 256 + threadIdx.x;
  if (v < NN) {
    int d = deg[v];
    dis[v] = d > 0 ? rsqrtf((float)d) : 0.0f;
  }
  if (blockIdx.x == 0) {
    int t = threadIdx.x;
    if (t < 8)       ((unsigned int*)u00)[(size_t)NN * 8 + t] = 0;
    else if (t < 16) ((unsigned int*)u01)[(size_t)NN * 8 + (t - 8)] = 0;
    else if (t < 24) ((unsigned int*)u10)[(size_t)NN * 8 + (t - 16)] = 0;
    else if (t < 32) ((unsigned int*)u11)[(size_t)NN * 8 + (t - 24)] = 0;
  }
}

// ---------------- exclusive scan over deg rounded-up-to-4 ----------------
__global__ __launch_bounds__(256) void k_scan1(const int* __restrict__ deg,
                                               int* __restrict__ rp,
                                               int* __restrict__ part) {
  __shared__ int s[256];
  int b = blockIdx.x, t = threadIdx.x;
  int base = b * 1024 + t * 4;
  int v0 = (base + 0 < NN) ? ((deg[base + 0] + 3) & ~3) : 0;
  int v1 = (base + 1 < NN) ? ((deg[base + 1] + 3) & ~3) : 0;
  int v2 = (base + 2 < NN) ? ((deg[base + 2] + 3) & ~3) : 0;
  int v3 = (base + 3 < NN) ? ((deg[base + 3] + 3) & ~3) : 0;
  int tot = v0 + v1 + v2 + v3;
  s[t] = tot;
  __syncthreads();
  for (int d = 1; d < 256; d <<= 1) {
    int x = (t >= d) ? s[t - d] : 0;
    __syncthreads();
    s[t] += x;
    __syncthreads();
  }
  int excl = s[t] - tot;
  if (t == 255) part[b] = s[255];
  if (base + 0 < NN) rp[base + 0] = excl;
  if (base + 1 < NN) rp[base + 1] = excl + v0;
  if (base + 2 < NN) rp[base + 2] = excl + v0 + v1;
  if (base + 3 < NN) rp[base + 3] = excl + v0 + v1 + v2;
}

__global__ __launch_bounds__(128) void k_scan2(const int* __restrict__ part,
                                               int* __restrict__ offs) {
  __shared__ int s[128];
  int t = threadIdx.x;
  int v = (t < 98) ? part[t] : 0;
  s[t] = v;
  __syncthreads();
  for (int d = 1; d < 128; d <<= 1) {
    int x = (t >= d) ? s[t - d] : 0;
    __syncthreads();
    s[t] += x;
    __syncthreads();
  }
  if (t < 98) offs[t] = s[t] - v;
}

__global__ __launch_bounds__(256) void k_scan3(int* __restrict__ rp,
                                               const int* __restrict__ offs,
                                               const int* __restrict__ part,
                                               int* __restrict__ cur) {
  int b = blockIdx.x, t = threadIdx.x;
  int o = offs[b];
  int base = b * 1024 + t * 4;
#pragma unroll
  for (int j = 0; j < 4; ++j) {
    int i = base + j;
    if (i < NN) {
      int r = rp[i] + o;
      rp[i] = r;
      cur[i] = r;
    }
  }
  if (b == 0 && t == 0) rp[NN] = offs[97] + part[97];
}

// fill CSR src-only
__global__ __launch_bounds__(256) void k_fill(const int* __restrict__ ei,
                                              int* __restrict__ cur,
                                              int* __restrict__ csrc) {
  int e = blockIdx.x * 256 + threadIdx.x;
  if (e < NE) {
    int c = ei[NE + e];
    int p = atomicAdd(&cur[c], 1);
    csrc[p] = ei[e];
  }
}

// pad each node's slots up to rounded length with dummy src = NN (zero row)
__global__ __launch_bounds__(256) void k_pad(const int* __restrict__ cur,
                                             const int* __restrict__ rp,
                                             int* __restrict__ csrc) {
  int v = blockIdx.x * 256 + threadIdx.x;
  if (v < NN) {
    int p = cur[v], e = rp[v + 1];
    for (; p < e; ++p) csrc[p] = NN;
  }
}

// ---------------- split-transpose: dst[n][k] = split(src[k][n]) ----------------
__global__ __launch_bounds__(256) void k_splitT(const float* __restrict__ src,
                                                unsigned short* __restrict__ dh,
                                                unsigned short* __restrict__ dl,
                                                int K, int N) {
  int idx = blockIdx.x * 256 + threadIdx.x;
  if (idx >= K * N) return;
  int n = idx / K, k = idx - n * K;
  float v = src[(size_t)k * N + n];
  unsigned short h = bf16_rne(v);
  dh[idx] = h;
  dl[idx] = bf16_rne(v - bf16_to_f32(h));
}

// ---------------- GEMM1 (r4 structure, unchanged): H1bf = bf16(relu(X@W1+b1)) ----
__global__ __launch_bounds__(512, 2) void k_gemm1(const float* __restrict__ X,
                                                  const unsigned short* __restrict__ W1Th,
                                                  const unsigned short* __restrict__ W1Tl,
                                                  const float* __restrict__ bias1,
                                                  unsigned short* __restrict__ H1bf) {
  __shared__ __align__(16) unsigned short Ah[2][4096];
  __shared__ __align__(16) unsigned short Bh[2][8192], Bl[2][8192];
  const int t = threadIdx.x;
  const int m0 = blockIdx.x * 128;
  const int w = t >> 6, lane = t & 63;
  const int wm = w >> 2, wn = w & 3;

  const int arow = t >> 2;
  const int achk = t & 3;
  int axrow = m0 + arow; if (axrow >= NN) axrow = NN - 1;
  const float* aptr = X + (size_t)axrow * INCH + achk * 8;
  int aidx = (arow >> 4) * 512 + ((arow & 15) + achk * 16) * 8;
  aidx ^= ((aidx >> 7) & 3) << 4;
  const int aroff = (lane * 8) ^ (((lane >> 4) & 3) << 4);

  const int bn0 = (w * 16) + (lane & 15);
  const int bko = (lane >> 4) * 8;
  const unsigned short* bs0 = W1Th + (size_t)bn0 * INCH + bko;
  const unsigned short* bs1 = W1Th + (size_t)(bn0 + 128) * INCH + bko;
  const unsigned short* bs2 = W1Tl + (size_t)bn0 * INCH + bko;
  const unsigned short* bs3 = W1Tl + (size_t)(bn0 + 128) * INCH + bko;

  f32x4 acc[4][4] = {};
  float4 av0, av1;

  av0 = *(const float4*)(aptr);
  av1 = *(const float4*)(aptr + 4);
  GLOAD_LDS16(bs0, &Bh[0][w * 512]);
  GLOAD_LDS16(bs1, &Bh[0][(w + 8) * 512]);
  GLOAD_LDS16(bs2, &Bl[0][w * 512]);
  GLOAD_LDS16(bs3, &Bl[0][(w + 8) * 512]);
  {
    float af[8] = {av0.x, av0.y, av0.z, av0.w, av1.x, av1.y, av1.z, av1.w};
    short8 ah;
#pragma unroll
    for (int i = 0; i < 8; ++i) {
      unsigned int u = __float_as_uint(af[i]);
      ah[i] = (short)((u + 0x7fffu + ((u >> 16) & 1u)) >> 16);
    }
    *(short8*)&Ah[0][aidx] = ah;
  }
  __syncthreads();

#pragma unroll
  for (int it = 0; it < 16; ++it) {
    const int cur = it & 1, nxt = cur ^ 1;
    const int k0 = it * 32;
    if (it < 15) {
      av0 = *(const float4*)(aptr + k0 + 32);
      av1 = *(const float4*)(aptr + k0 + 36);
      GLOAD_LDS16(bs0 + k0 + 32, &Bh[nxt][w * 512]);
      GLOAD_LDS16(bs1 + k0 + 32, &Bh[nxt][(w + 8) * 512]);
      GLOAD_LDS16(bs2 + k0 + 32, &Bl[nxt][w * 512]);
      GLOAD_LDS16(bs3 + k0 + 32, &Bl[nxt][(w + 8) * 512]);
    }
    short8 afrag[4];
#pragma unroll
    for (int mf = 0; mf < 4; ++mf)
      afrag[mf] = *(const short8*)&Ah[cur][(wm * 4 + mf) * 512 + aroff];
#pragma unroll
    for (int nf = 0; nf < 4; ++nf) {
      short8 bfh = *(const short8*)&Bh[cur][(wn * 4 + nf) * 512 + lane * 8];
      short8 bfl = *(const short8*)&Bl[cur][(wn * 4 + nf) * 512 + lane * 8];
#pragma unroll
      for (int mf = 0; mf < 4; ++mf) {
        acc[mf][nf] = __builtin_amdgcn_mfma_f32_16x16x32_bf16(afrag[mf], bfh, acc[mf][nf], 0, 0, 0);
        acc[mf][nf] = __builtin_amdgcn_mfma_f32_16x16x32_bf16(afrag[mf], bfl, acc[mf][nf], 0, 0, 0);
      }
    }
    if (it < 15) {
      float af[8] = {av0.x, av0.y, av0.z, av0.w, av1.x, av1.y, av1.z, av1.w};
      short8 ah;
#pragma unroll
      for (int i = 0; i < 8; ++i) {
        unsigned int u = __float_as_uint(af[i]);
        ah[i] = (short)((u + 0x7fffu + ((u >> 16) & 1u)) >> 16);
      }
      *(short8*)&Ah[nxt][aidx] = ah;
    }
    __syncthreads();
  }

  const int colbase = wn * 64 + (lane & 15);
  const int rowbase = m0 + wm * 64 + ((lane >> 4) << 2);
#pragma unroll
  for (int nf = 0; nf < 4; ++nf) {
    int col = colbase + nf * 16;
    float b = bias1[col];
#pragma unroll
    for (int mf = 0; mf < 4; ++mf) {
#pragma unroll
      for (int r = 0; r < 4; ++r) {
        int row = rowbase + mf * 16 + r;
        if (row < NN) {
          float h = fmaxf(acc[mf][nf][r] + b, 0.f);
          H1bf[(size_t)row * HIDCH + col] = bf16_rne(h);
        }
      }
    }
  }
}

// ---------------- GEMM2: h = H1bf @ W2 + b2; write u0 halves + oacc init ----------
__global__ __launch_bounds__(256) void k_gemm2(const unsigned short* __restrict__ H1bf,
                                               const unsigned short* __restrict__ W2Th,
                                               const unsigned short* __restrict__ W2Tl,
                                               const float* __restrict__ bias2,
                                               const float* __restrict__ gamma,
                                               const float* __restrict__ dis,
                                               unsigned short* __restrict__ u00,
                                               unsigned short* __restrict__ u01,
                                               float* __restrict__ oa0,
                                               float* __restrict__ oa1) {
  __shared__ __align__(16) unsigned short A2[8192];
  __shared__ __align__(16) unsigned short B2h[2048], B2l[2048];
  const int t = threadIdx.x;
  const int m0 = blockIdx.x * 128;

  const int arow = t >> 1;
  int axrow = m0 + arow; if (axrow >= NN) axrow = NN - 1;
  const int akb = (t & 1) * 32;
  const unsigned short* ap = H1bf + (size_t)axrow * HIDCH + akb;
  const int abase = ((arow >> 4) * 2 + (akb >> 5)) * 512 + (arow & 15) * 8;

  const int bnr = t >> 3, bkq = (t & 7) * 8;
  const int bslot = ((bnr >> 4) * 2 + (bkq >> 5)) * 512 +
                    ((bnr & 15) + (((bkq & 31) >> 3) << 4)) * 8;
  const unsigned short* bhp = W2Th + (size_t)bnr * HIDCH + bkq;
  const unsigned short* blp = W2Tl + (size_t)bnr * HIDCH + bkq;

  const int w = t >> 6, lane = t & 63;

  f32x4 acc[2][2] = {};

  for (int k0 = 0; k0 < HIDCH; k0 += 64) {
    uint4 a0 = *(const uint4*)(ap + k0);
    uint4 a1 = *(const uint4*)(ap + k0 + 8);
    uint4 a2 = *(const uint4*)(ap + k0 + 16);
    uint4 a3 = *(const uint4*)(ap + k0 + 24);
    uint4 bh = *(const uint4*)(bhp + k0);
    uint4 bl = *(const uint4*)(blp + k0);

    __syncthreads();

    *(uint4*)&A2[abase + 0 * 128] = a0;
    *(uint4*)&A2[abase + 1 * 128] = a1;
    *(uint4*)&A2[abase + 2 * 128] = a2;
    *(uint4*)&A2[abase + 3 * 128] = a3;
    *(uint4*)&B2h[bslot] = bh;
    *(uint4*)&B2l[bslot] = bl;

    __syncthreads();

    const short8* AV  = (const short8*)A2;
    const short8* BHV = (const short8*)B2h;
    const short8* BLV = (const short8*)B2l;
#pragma unroll
    for (int k32 = 0; k32 < 2; ++k32) {
      short8 bfh[2], bfl[2];
#pragma unroll
      for (int nf = 0; nf < 2; ++nf) {
        bfh[nf] = BHV[(nf * 2 + k32) * 64 + lane];
        bfl[nf] = BLV[(nf * 2 + k32) * 64 + lane];
      }
#pragma unroll
      for (int mf = 0; mf < 2; ++mf) {
        short8 a = AV[((w * 2 + mf) * 2 + k32) * 64 + lane];
#pragma unroll
        for (int nf = 0; nf < 2; ++nf) {
          acc[mf][nf] = __builtin_amdgcn_mfma_f32_16x16x32_bf16(a, bfh[nf], acc[mf][nf], 0, 0, 0);
          acc[mf][nf] = __builtin_amdgcn_mfma_f32_16x16x32_bf16(a, bfl[nf], acc[mf][nf], 0, 0, 0);
        }
      }
    }
  }

  const float g0 = gamma[0];
  const int colb = lane & 15;
  const int rowb = m0 + w * 32 + ((lane >> 4) << 2);
  const float b2c0 = bias2[colb], b2c1 = bias2[16 + colb];
#pragma unroll
  for (int mf = 0; mf < 2; ++mf) {
#pragma unroll
    for (int r = 0; r < 4; ++r) {
      int row = rowb + mf * 16 + r;
      if (row < NN) {
        float dv = dis[row];
        float h0 = acc[mf][0][r] + b2c0;
        float h1 = acc[mf][1][r] + b2c1;
        size_t o = (size_t)row * 16 + colb;
        u00[o] = bf16_rne(dv * h0);
        u01[o] = bf16_rne(dv * h1);
        oa0[o] = g0 * h0;
        oa1[o] = g0 * h1;
      }
    }
  }
}

// ---------------- hop: both halves in ONE dispatch, XCD-steered ----------------
// 8-lane group per node (16 ch bf16 = 32B row). NO LDS: meta int4 loaded with
// uniform address across the 8-lane group (hardware broadcast), 8-edge unroll
// so 10 VMEM ops issue before the accumulate chain.
__global__ __launch_bounds__(256) void k_hop(
    const unsigned short* __restrict__ uin0, const unsigned short* __restrict__ uin1,
    unsigned short* __restrict__ uout0, unsigned short* __restrict__ uout1,
    float* __restrict__ oa0, float* __restrict__ oa1,
    const int* __restrict__ rp, const int* __restrict__ csrc,
    const float* __restrict__ dis, const float* __restrict__ gamma, int k) {
  const int bid = blockIdx.x;
  const int xcd = bid & 7;                 // default bid->XCD mapping is bid%8
  const int half = xcd >> 2;               // XCDs 0-3: half 0; XCDs 4-7: half 1
  const int hidx = (bid >> 3) * 4 + (xcd & 3);
  if (hidx >= NN / 32) return;
  const unsigned short* __restrict__ Uin = half ? uin1 : uin0;
  unsigned short* __restrict__ Uout = half ? uout1 : uout0;
  float* __restrict__ oacc = half ? oa1 : oa0;

  const int t = threadIdx.x;
  const int g = t >> 3;                    // node slot 0..31
  const int li = t & 7;                    // lane in group (2 channels each)
  const int v = hidx * 32 + g;
  const int s = rp[v], e = rp[v + 1];      // multiples of 4 (padded, src=NN -> zero row)

  float ax0 = 0.f, ay0 = 0.f, ax1 = 0.f, ay1 = 0.f;
  float ax2 = 0.f, ay2 = 0.f, ax3 = 0.f, ay3 = 0.f;
  int j = s;
  for (; j + 8 <= e; j += 8) {
    int4 sa = *(const int4*)&csrc[j];      // uniform in group -> broadcast
    int4 sb = *(const int4*)&csrc[j + 4];
    unsigned int w0 = *(const unsigned int*)&Uin[(size_t)sa.x * 16 + li * 2];
    unsigned int w1 = *(const unsigned int*)&Uin[(size_t)sa.y * 16 + li * 2];
    unsigned int w2 = *(const unsigned int*)&Uin[(size_t)sa.z * 16 + li * 2];
    unsigned int w3 = *(const unsigned int*)&Uin[(size_t)sa.w * 16 + li * 2];
    unsigned int w4 = *(const unsigned int*)&Uin[(size_t)sb.x * 16 + li * 2];
    unsigned int w5 = *(const unsigned int*)&Uin[(size_t)sb.y * 16 + li * 2];
    unsigned int w6 = *(const unsigned int*)&Uin[(size_t)sb.z * 16 + li * 2];
    unsigned int w7 = *(const unsigned int*)&Uin[(size_t)sb.w * 16 + li * 2];
    ax0 += bflo(w0); ay0 += bfhi(w0);
    ax1 += bflo(w1); ay1 += bfhi(w1);
    ax2 += bflo(w2); ay2 += bfhi(w2);
    ax3 += bflo(w3); ay3 += bfhi(w3);
    ax0 += bflo(w4); ay0 += bfhi(w4);
    ax1 += bflo(w5); ay1 += bfhi(w5);
    ax2 += bflo(w6); ay2 += bfhi(w6);
    ax3 += bflo(w7); ay3 += bfhi(w7);
  }
  if (j < e) {                             // remaining 4 (e-s is a multiple of 4)
    int4 sa = *(const int4*)&csrc[j];
    unsigned int w0 = *(const unsigned int*)&Uin[(size_t)sa.x * 16 + li * 2];
    unsigned int w1 = *(const unsigned int*)&Uin[(size_t)sa.y * 16 + li * 2];
    unsigned int w2 = *(const unsigned int*)&Uin[(size_t)sa.z * 16 + li * 2];
    unsigned int w3 = *(const unsigned int*)&Uin[(size_t)sa.w * 16 + li * 2];
    ax0 += bflo(w0); ay0 += bfhi(w0);
    ax1 += bflo(w1); ay1 += bfhi(w1);
    ax2 += bflo(w2); ay2 += bfhi(w2);
    ax3 += bflo(w3); ay3 += bfhi(w3);
  }
  const float Sx = (ax0 + ax1) + (ax2 + ax3);
  const float Sy = (ay0 + ay1) + (ay2 + ay3);
  const float dv = dis[v];
  const float gd = gamma[k] * dv;
  const float d2 = dv * dv;
  unsigned int packed = (unsigned int)bf16_rne(d2 * Sx) |
                        ((unsigned int)bf16_rne(d2 * Sy) << 16);
  ((unsigned int*)Uout)[(size_t)v * 8 + li] = packed;
  float2 po = *(const float2*)&oacc[(size_t)v * 16 + li * 2];
  po.x = fmaf(gd, Sx, po.x);
  po.y = fmaf(gd, Sy, po.y);
  *(float2*)&oacc[(size_t)v * 16 + li * 2] = po;
}

// ---------------- merge oacc halves -> out [NN][32] ----------------
__global__ __launch_bounds__(256) void k_merge(const float* __restrict__ oa0,
                                               const float* __restrict__ oa1,
                                               float* __restrict__ out) {
  int i4 = blockIdx.x * 256 + threadIdx.x;          // float4 index, NN*8 total
  if (i4 >= NN * 8) return;
  int v = i4 >> 3;
  int j = (i4 & 7) * 4;                              // 0,4,...,28
  const float* src = (j < 16) ? oa0 : oa1;
  float4 val = *(const float4*)&src[(size_t)v * 16 + (j & 15)];
  *(float4*)&out[(size_t)v * 32 + j] = val;
}

extern "C" void kernel_launch(void* const* d_in, const int* in_sizes, int n_in,
                              void* d_out, int out_size, void* d_ws, size_t ws_size,
                              hipStream_t stream) {
  const float* x     = (const float*)d_in[0];
  const int*   ei    = (const int*)d_in[1];
  const float* W1    = (const float*)d_in[2];
  const float* b1    = (const float*)d_in[3];
  const float* W2    = (const float*)d_in[4];
  const float* b2    = (const float*)d_in[5];
  const float* gamma = (const float*)d_in[6];
  float* out = (float*)d_out;

  char* ws = (char*)d_ws;
  unsigned short* h1bf = (unsigned short*)(ws + OFF_H1);
  unsigned short* U[2][2] = {
    {(unsigned short*)(ws + OFF_U00), (unsigned short*)(ws + OFF_U01)},
    {(unsigned short*)(ws + OFF_U10), (unsigned short*)(ws + OFF_U11)}};
  float* oa0 = (float*)(ws + OFF_OA0);
  float* oa1 = (float*)(ws + OFF_OA1);
  unsigned short* w1th = (unsigned short*)(ws + OFF_W1TH);
  unsigned short* w1tl = (unsigned short*)(ws + OFF_W1TL);
  unsigned short* w2th = (unsigned short*)(ws + OFF_W2TH);
  unsigned short* w2tl = (unsigned short*)(ws + OFF_W2TL);
  int*   deg  = (int*)(ws + OFF_DEG);
  float* dis  = (float*)(ws + OFF_DIS);
  int*   rp   = (int*)(ws + OFF_RP);
  int*   cur  = (int*)(ws + OFF_CUR);
  int*   csrc = (int*)(ws + OFF_CSR);
  int*   part = (int*)(ws + OFF_PART);
  int*   offs = (int*)(ws + OFF_OFFS);

  hipMemsetAsync(deg, 0, NN * sizeof(int), stream);

  // weight prep (tiny)
  k_splitT<<<(INCH * HIDCH + 255) / 256, 256, 0, stream>>>(W1, w1th, w1tl, INCH, HIDCH);
  k_splitT<<<(HIDCH * OUTCH + 255) / 256, 256, 0, stream>>>(W2, w2th, w2tl, HIDCH, OUTCH);

  // graph prep
  k_count_deg<<<(NE + 255) / 256, 256, 0, stream>>>(ei + NE, deg);
  k_dis<<<(NN + 255) / 256, 256, 0, stream>>>(deg, dis, U[0][0], U[0][1], U[1][0], U[1][1]);
  k_scan1<<<98, 256, 0, stream>>>(deg, rp, part);
  k_scan2<<<1, 128, 0, stream>>>(part, offs);
  k_scan3<<<98, 256, 0, stream>>>(rp, offs, part, cur);
  k_fill<<<(NE + 255) / 256, 256, 0, stream>>>(ei, cur, csrc);
  k_pad<<<(NN + 255) / 256, 256, 0, stream>>>(cur, rp, csrc);

  // MLP
  k_gemm1<<<(NN + 127) / 128, 512, 0, stream>>>(x, w1th, w1tl, b1, h1bf);
  k_gemm2<<<(NN + 127) / 128, 256, 0, stream>>>(h1bf, w2th, w2tl, b2, gamma, dis,
                                                U[0][0], U[0][1], oa0, oa1);

  // propagation: 10 dispatches; each covers both channel-halves (XCD-steered)
  const int hop_grid = ((NN / 32 + 3) / 4) * 8;   // 782*8 = 6256
  for (int k = 1; k <= KHOPS; ++k) {
    const int pin = (k - 1) & 1, pout = k & 1;
    k_hop<<<hop_grid, 256, 0, stream>>>(U[pin][0], U[pin][1], U[pout][0], U[pout][1],
                                        oa0, oa1, rp, csrc, dis, gamma, k);
  }

  k_merge<<<(NN * 8 + 255) / 256, 256, 0, stream>>>(oa0, oa1, out);
}